// Round 6
// baseline (693.996 us; speedup 1.0000x reference)
//
#include <hip/hip_runtime.h>
#include <stdint.h>

using f16 = _Float16;
typedef __attribute__((ext_vector_type(8))) f16 f16x8;
typedef __attribute__((ext_vector_type(4))) float f32x4;

constexpr int N = 1024;

__device__ __forceinline__ float leaky(float v) { return v >= 0.f ? v : 0.01f * v; }

// ---------------------------------------------------------------------------
// Phase A: BinaryTreeConv  Yc^T[n][o] = sum_kap Xg[n][kap] * Wfc[kap][o] + bc
// NO LDS, NO barriers: A-fragments are loaded straight from global memory —
// the 16x16x32 A-layout (lane l: row l&15, kap 8*(l>>4)..+7) is exactly a
// 16B-per-lane gather, identical coalescing to the old LDS-staging DMA.
// Row redundancy across waves is absorbed by L2/L3 (X batch = 328KB).
// Waves run barrier-free; compiler pipelines loads (unroll 2).
// Tile: 64 nodes x CO per block, 4 waves = 2 n-groups x 2 o-groups.
// ---------------------------------------------------------------------------
template<int CI, int CO>
__global__ __launch_bounds__(256) void convA_kernel(
    const f16* __restrict__ X, const int* __restrict__ idx,
    const f16* __restrict__ Wf, const float* __restrict__ bc,
    f16* __restrict__ yc, float2* __restrict__ part)
{
    constexpr int U = CO / 16, UW = CO / 32;
    static_assert(CI % 32 == 0, "seg boundaries must align to 32-kap chunks");

    __shared__ float redu[8];

    const int tid = threadIdx.x;
    const int w = tid >> 6, l = tid & 63;
    const int wn = w & 1, wo = w >> 1;
    const int n0 = blockIdx.x * 64;
    const int b = blockIdx.y;

    // per-lane gather rows for this lane's two A-fragment rows (rt = 0,1)
    int rows[2][3];
    #pragma unroll
    for (int rt = 0; rt < 2; ++rt) {
        int n = n0 + 32 * wn + 16 * rt + (l & 15);
        const int* ip = idx + (size_t)b * 3 * N + 3 * n;
        rows[rt][0] = ip[0]; rows[rt][1] = ip[1]; rows[rt][2] = ip[2];
    }
    const f16* xb = X + (size_t)b * N * CI;
    const int koff = 8 * (l >> 4);

    f32x4 acc[2][UW] = {};

    #pragma unroll
    for (int seg = 0; seg < 3; ++seg) {
        const f16* a0 = xb + (size_t)rows[0][seg] * CI + koff;
        const f16* a1 = xb + (size_t)rows[1][seg] * CI + koff;
        const f16* wp = Wf + ((size_t)seg * (CI / 32) * U + wo * UW) * 512 + l * 8;
        #pragma unroll 2
        for (int sk = 0; sk < CI / 32; ++sk) {
            f16x8 av0 = *(const f16x8*)(a0 + 32 * sk);
            f16x8 av1 = *(const f16x8*)(a1 + 32 * sk);
            #pragma unroll
            for (int uu = 0; uu < UW; ++uu) {
                f16x8 wv = *(const f16x8*)(wp + ((size_t)sk * U + uu) * 512);
                acc[0][uu] = __builtin_amdgcn_mfma_f32_16x16x32_f16(av0, wv, acc[0][uu], 0, 0, 0);
                acc[1][uu] = __builtin_amdgcn_mfma_f32_16x16x32_f16(av1, wv, acc[1][uu], 0, 0, 0);
            }
        }
    }

    // epilogue: bias, store f16, per-tree stats partials
    float p1 = 0.f, p2 = 0.f;
    #pragma unroll
    for (int rt = 0; rt < 2; ++rt) {
        #pragma unroll
        for (int uu = 0; uu < UW; ++uu) {
            int o = wo * (CO / 2) + uu * 16 + (l & 15);
            float bcv = bc[o];
            size_t rb = ((size_t)b * N + (n0 + 32 * wn + 16 * rt + 4 * (l >> 4))) * CO + o;
            #pragma unroll
            for (int j = 0; j < 4; ++j) {
                float v = acc[rt][uu][j] + bcv;
                yc[rb + (size_t)j * CO] = (f16)v;
                p1 += v; p2 += v * v;
            }
        }
    }
    #pragma unroll
    for (int m = 32; m; m >>= 1) { p1 += __shfl_xor(p1, m); p2 += __shfl_xor(p2, m); }
    if (l == 0) { redu[w * 2] = p1; redu[w * 2 + 1] = p2; }
    __syncthreads();
    if (tid == 0)
        part[(size_t)b * 16 + blockIdx.x] =
            make_float2(redu[0] + redu[2] + redu[4] + redu[6],
                        redu[1] + redu[3] + redu[5] + redu[7]);
}

__global__ __launch_bounds__(64) void reduce_stats_kernel(
    const float2* __restrict__ part, float2* __restrict__ stats, int nparts, float Mf)
{
    int b = blockIdx.x;
    float s1 = 0.f, s2 = 0.f;
    for (int i = threadIdx.x; i < nparts; i += 64) {
        float2 p = part[(size_t)b * nparts + i];
        s1 += p.x; s2 += p.y;
    }
    #pragma unroll
    for (int m = 32; m; m >>= 1) { s1 += __shfl_xor(s1, m); s2 += __shfl_xor(s2, m); }
    if (threadIdx.x == 0) {
        float mu = s1 / Mf;
        float var = (s2 - s1 * s1 / Mf) / (Mf - 1.f);   // ddof = 1
        var = fmaxf(var, 0.f);
        stats[b] = make_float2(mu, 1.f / (sqrtf(var) + 1e-5f));
    }
}

// ---------------------------------------------------------------------------
// Phase B: ChannelMixer GEMM (K = CI, identity rows). Direct register loads
// (contiguous rows), no LDS, no barriers. TreeLayerNorm + leaky fused into
// the epilogue: x = leaky(ym + (yc-mu)*inv), written in place over yc.
// ---------------------------------------------------------------------------
template<int CI, int CO>
__global__ __launch_bounds__(256) void mixB_kernel(
    const f16* __restrict__ X, const f16* __restrict__ Wf, const float* __restrict__ bm,
    f16* __restrict__ y, const float2* __restrict__ stats)
{
    constexpr int U = CO / 16, UW = CO / 32;

    const int tid = threadIdx.x;
    const int w = tid >> 6, l = tid & 63;
    const int wn = w & 1, wo = w >> 1;
    const int n0 = blockIdx.x * 64;
    const int b = blockIdx.y;

    const f16* xb = X + (size_t)b * N * CI;
    const int koff = 8 * (l >> 4);
    const f16* a0 = xb + (size_t)(n0 + 32 * wn + (l & 15)) * CI + koff;
    const f16* a1 = a0 + 16 * CI;

    f32x4 acc[2][UW] = {};
    const f16* wp = Wf + (size_t)(wo * UW) * 512 + l * 8;

    #pragma unroll 2
    for (int sk = 0; sk < CI / 32; ++sk) {
        f16x8 av0 = *(const f16x8*)(a0 + 32 * sk);
        f16x8 av1 = *(const f16x8*)(a1 + 32 * sk);
        #pragma unroll
        for (int uu = 0; uu < UW; ++uu) {
            f16x8 wv = *(const f16x8*)(wp + ((size_t)sk * U + uu) * 512);
            acc[0][uu] = __builtin_amdgcn_mfma_f32_16x16x32_f16(av0, wv, acc[0][uu], 0, 0, 0);
            acc[1][uu] = __builtin_amdgcn_mfma_f32_16x16x32_f16(av1, wv, acc[1][uu], 0, 0, 0);
        }
    }

    const float2 st = stats[b];
    #pragma unroll
    for (int rt = 0; rt < 2; ++rt) {
        #pragma unroll
        for (int uu = 0; uu < UW; ++uu) {
            int o = wo * (CO / 2) + uu * 16 + (l & 15);
            float bmv = bm[o];
            size_t rb = ((size_t)b * N + (n0 + 32 * wn + 16 * rt + 4 * (l >> 4))) * CO + o;
            #pragma unroll
            for (int j = 0; j < 4; ++j) {
                size_t off = rb + (size_t)j * CO;
                float ycv = (float)y[off];
                float v = acc[rt][uu][j] + bmv + (ycv - st.x) * st.y;
                y[off] = (f16)leaky(v);
            }
        }
    }
}

// fp32 [B][160][N] -> f16 [B][N][160]
__global__ __launch_bounds__(256) void transpose_kernel(
    const float* __restrict__ trees, f16* __restrict__ X0)
{
    __shared__ f16 tile[32][66];
    int b = blockIdx.z, c0 = blockIdx.y * 32, n0 = blockIdx.x * 64;
    int tid = threadIdx.x;
    int nl = tid & 63, c4 = tid >> 6;
    #pragma unroll
    for (int cc = 0; cc < 8; ++cc) {
        int c = c4 * 8 + cc;
        tile[c][nl] = (f16)trees[((size_t)b * 160 + c0 + c) * N + n0 + nl];
    }
    __syncthreads();
    int nn = tid >> 2, gc = tid & 3;
    f16x8 pack;
    #pragma unroll
    for (int e = 0; e < 8; ++e) pack[e] = tile[gc * 8 + e][nn];
    *(f16x8*)(X0 + ((size_t)b * N + n0 + nn) * 160 + c0 + gc * 8) = pack;
}

// weights -> fragment-ready f16 layout: elem ((skk*U+u)*64+l)*8+j  holds
// W[kap = 32*skk+8*(l>>4)+j][o = 16u+(l&15)], kappa-order kap = k*CI + c.
__global__ __launch_bounds__(256) void prepW_kernel(
    const float* __restrict__ Wsrc, f16* __restrict__ out,
    int K, int CO, int CI, int isconv)
{
    int e = blockIdx.x * 256 + threadIdx.x;
    if (e >= K * CO) return;
    int j = e & 7, l = (e >> 3) & 63, r = e >> 9;
    int U = CO / 16;
    int u = r % U, t = r / U;
    int kap = 32 * t + 8 * (l >> 4) + j;
    int o = 16 * u + (l & 15);
    float v = isconv ? Wsrc[((size_t)o * CI + (kap % CI)) * 3 + kap / CI]
                     : Wsrc[(size_t)o * CI + kap];
    out[e] = (f16)v;
}

// masked max-pool over valid nodes + 64->32->1 MLP; x3 is [b][n][64] f16.
__global__ __launch_bounds__(256) void final_kernel(
    const f16* __restrict__ x3, const int* __restrict__ nodes,
    const float* __restrict__ W1, const float* __restrict__ b1,
    const float* __restrict__ W2, const float* __restrict__ b2,
    float* __restrict__ out)
{
    int b = blockIdx.x, tid = threadIdx.x;
    int o = tid & 63, r = tid >> 6;
    int nv = nodes[b];
    const f16* p = x3 + (size_t)b * N * 64 + o;
    float mx = -3.4e38f;
    for (int n = r; n < nv; n += 4) mx = fmaxf(mx, (float)p[(size_t)n * 64]);
    __shared__ float pool[4][64];
    __shared__ float pooled[64], hbuf[32];
    pool[r][o] = mx;
    __syncthreads();
    if (tid < 64) pooled[tid] = fmaxf(fmaxf(pool[0][tid], pool[1][tid]),
                                      fmaxf(pool[2][tid], pool[3][tid]));
    __syncthreads();
    if (tid < 32) {
        float h = b1[tid];
        #pragma unroll 8
        for (int oo = 0; oo < 64; ++oo) h += pooled[oo] * W1[oo * 32 + tid];
        hbuf[tid] = leaky(h);
    }
    __syncthreads();
    if (tid == 0) {
        float rr = b2[0];
        for (int jj = 0; jj < 32; ++jj) rr += hbuf[jj] * W2[jj];
        out[b] = rr;
    }
}

extern "C" void kernel_launch(void* const* d_in, const int* in_sizes, int n_in,
                              void* d_out, int out_size, void* d_ws, size_t ws_size,
                              hipStream_t stream)
{
    (void)in_sizes; (void)n_in; (void)out_size; (void)ws_size;
    const float* trees = (const float*)d_in[0];
    const int* indexes = (const int*)d_in[1];
    const int* nodes   = (const int*)d_in[2];
    const float* Wc1 = (const float*)d_in[3];
    const float* bc1 = (const float*)d_in[4];
    const float* Wm1 = (const float*)d_in[5];
    const float* bm1 = (const float*)d_in[6];
    const float* Wc2 = (const float*)d_in[7];
    const float* bc2 = (const float*)d_in[8];
    const float* Wm2 = (const float*)d_in[9];
    const float* bm2 = (const float*)d_in[10];
    const float* Wc3 = (const float*)d_in[11];
    const float* bc3 = (const float*)d_in[12];
    const float* Wm3 = (const float*)d_in[13];
    const float* bm3 = (const float*)d_in[14];
    const float* W1 = (const float*)d_in[15];
    const float* b1 = (const float*)d_in[16];
    const float* W2 = (const float*)d_in[17];
    const float* b2 = (const float*)d_in[18];
    float* out = (float*)d_out;

    // ws layout:
    //   [0, 83886080)            X0 [B][N][160] f16      -> later yc2/x2 (67MB)
    //   [83886080, 218103808)    yc1/x1 [B][N][256] f16  -> later yc3/x3 (33.5MB)
    //   [218103808, ...)         Wfrags, parts, stats
    char* ws = (char*)d_ws;
    f16* X0 = (f16*)ws;
    f16* A1 = (f16*)(ws + 83886080);
    f16* A2 = (f16*)ws;
    f16* A3 = A1;
    size_t toff = 218103808;
    f16* Wfc1 = (f16*)(ws + toff); toff += (size_t)480 * 256 * 2;
    f16* Wfm1 = (f16*)(ws + toff); toff += (size_t)160 * 256 * 2;
    f16* Wfc2 = (f16*)(ws + toff); toff += (size_t)768 * 128 * 2;
    f16* Wfm2 = (f16*)(ws + toff); toff += (size_t)256 * 128 * 2;
    f16* Wfc3 = (f16*)(ws + toff); toff += (size_t)384 * 64 * 2;
    f16* Wfm3 = (f16*)(ws + toff); toff += (size_t)128 * 64 * 2;
    float2* part  = (float2*)(ws + toff); toff += (size_t)256 * 16 * 8;
    float2* stats = (float2*)(ws + toff);

    transpose_kernel<<<dim3(16, 5, 256), 256, 0, stream>>>(trees, X0);
    prepW_kernel<<<480 * 256 / 256, 256, 0, stream>>>(Wc1, Wfc1, 480, 256, 160, 1);
    prepW_kernel<<<160 * 256 / 256, 256, 0, stream>>>(Wm1, Wfm1, 160, 256, 160, 0);
    prepW_kernel<<<768 * 128 / 256, 256, 0, stream>>>(Wc2, Wfc2, 768, 128, 256, 1);
    prepW_kernel<<<256 * 128 / 256, 256, 0, stream>>>(Wm2, Wfm2, 256, 128, 256, 0);
    prepW_kernel<<<384 * 64 / 256, 256, 0, stream>>>(Wc3, Wfc3, 384, 64, 128, 1);
    prepW_kernel<<<128 * 64 / 256, 256, 0, stream>>>(Wm3, Wfm3, 128, 64, 128, 0);

    convA_kernel<160, 256><<<dim3(16, 256), 256, 0, stream>>>(X0, indexes, Wfc1, bc1, A1, part);
    reduce_stats_kernel<<<256, 64, 0, stream>>>(part, stats, 16, 262144.f);
    mixB_kernel<160, 256><<<dim3(16, 256), 256, 0, stream>>>(X0, Wfm1, bm1, A1, stats);

    convA_kernel<256, 128><<<dim3(16, 256), 256, 0, stream>>>(A1, indexes, Wfc2, bc2, A2, part);
    reduce_stats_kernel<<<256, 64, 0, stream>>>(part, stats, 16, 131072.f);
    mixB_kernel<256, 128><<<dim3(16, 256), 256, 0, stream>>>(A1, Wfm2, bm2, A2, stats);

    convA_kernel<128, 64><<<dim3(16, 256), 256, 0, stream>>>(A2, indexes, Wfc3, bc3, A3, part);
    reduce_stats_kernel<<<256, 64, 0, stream>>>(part, stats, 16, 65536.f);
    mixB_kernel<128, 64><<<dim3(16, 256), 256, 0, stream>>>(A2, Wfm3, bm3, A3, stats);

    final_kernel<<<256, 256, 0, stream>>>(A3, nodes, W1, b1, W2, b2, out);
}

// Round 7
// 579.435 us; speedup vs baseline: 1.1977x; 1.1977x over previous
//
#include <hip/hip_runtime.h>
#include <stdint.h>

using f16 = _Float16;
typedef __attribute__((ext_vector_type(8))) f16 f16x8;
typedef __attribute__((ext_vector_type(4))) float f32x4;

constexpr int N = 1024;

__device__ __forceinline__ float leaky(float v) { return v >= 0.f ? v : 0.01f * v; }

__device__ __forceinline__ void dma16(const void* g, void* l) {
    __builtin_amdgcn_global_load_lds(
        (const __attribute__((address_space(1))) uint32_t*)g,
        (__attribute__((address_space(3))) uint32_t*)l, 16, 0, 0);
}

// ---------------------------------------------------------------------------
// Unified GEMM for BinaryTreeConv (SEGS=3, gather) and ChannelMixer (SEGS=1,
// identity, ISMIX epilogue = fused TreeLayerNorm + leaky, in place).
//
// Key structure (r6 lesson: latency is the limiter, so minimize per-iter
// VMEM): W lives in LDS, staged ONCE per block (NSTG phases for conv2);
// A-fragments are loaded direct global->register (the 16x16x32 A layout is
// a native 16B-per-lane gather). Inner loop = 2 VMEM + 4 ds_read + 8 MFMA,
// no barriers. Block: 512 threads = 8 n-waves, tile 256n x 64o.
// ---------------------------------------------------------------------------
template<int CI, int CO, int SEGS, int NSTG, bool ISMIX>
__global__ __launch_bounds__(512) void gemm_kernel(
    const f16* __restrict__ X, const int* __restrict__ idx,
    const f16* __restrict__ Wf, const float* __restrict__ bias,
    f16* __restrict__ Y, float2* __restrict__ part,
    const float2* __restrict__ stats)
{
    constexpr int SKT = SEGS * CI / 32;     // total k-chunks of 32
    constexpr int KS32 = SKT / NSTG;        // k-chunks per staging phase
    constexpr int Ug = CO / 16;             // global o-subtile count
    constexpr int NGRAN = KS32 * 256;       // 16B granules per phase
    static_assert(CI % 32 == 0 && SKT % NSTG == 0, "geometry");

    __shared__ alignas(16) f16 lds[KS32 * 2048];   // [skl][uu][l][8]
    __shared__ float redu[16];

    const int tid = threadIdx.x;
    const int w = tid >> 6, l = tid & 63;
    const int n0 = blockIdx.x * 256;
    const int u0 = blockIdx.y * 4;          // o-block = 4 subtiles of 16
    const int b  = blockIdx.z;

    // per-lane A-row indices (gather for conv, identity for mix)
    int rows[2][SEGS];
    #pragma unroll
    for (int rt = 0; rt < 2; ++rt) {
        int n = n0 + 32 * w + 16 * rt + (l & 15);
        if constexpr (ISMIX) {
            rows[rt][0] = n;
        } else {
            const int* ip = idx + (size_t)b * 3 * N + 3 * n;
            #pragma unroll
            for (int s = 0; s < SEGS; ++s) rows[rt][s] = ip[s];
        }
    }
    const f16* xb = X + (size_t)b * N * CI;
    const int koff = 8 * (l >> 4);

    f32x4 acc[2][4] = {};

    #pragma unroll
    for (int p = 0; p < NSTG; ++p) {
        // stage phase-p W into LDS: dst is wave-linear (g = tid + 512r so the
        // 64 lanes of a wave fill consecutive 16B slots), src per-lane.
        for (int g = tid; g < NGRAN; g += 512) {
            int skk = g >> 8, uu = (g >> 6) & 3, ll = g & 63;
            dma16(Wf + (((size_t)(p * KS32 + skk) * Ug + u0 + uu) * 64 + ll) * 8,
                  (char*)lds + (size_t)g * 16);
        }
        __syncthreads();                     // drains vmcnt -> W visible

        #pragma unroll
        for (int skl = 0; skl < KS32; ++skl) {
            const int sk = p * KS32 + skl;
            const int seg = (sk * 32) / CI;              // compile-time
            const int co = sk * 32 - seg * CI + koff;
            f16x8 av0 = *(const f16x8*)(xb + (size_t)rows[0][seg] * CI + co);
            f16x8 av1 = *(const f16x8*)(xb + (size_t)rows[1][seg] * CI + co);
            #pragma unroll
            for (int uu = 0; uu < 4; ++uu) {
                f16x8 wv = *(const f16x8*)(lds + ((size_t)(skl * 4 + uu) * 64 + l) * 8);
                acc[0][uu] = __builtin_amdgcn_mfma_f32_16x16x32_f16(av0, wv, acc[0][uu], 0, 0, 0);
                acc[1][uu] = __builtin_amdgcn_mfma_f32_16x16x32_f16(av1, wv, acc[1][uu], 0, 0, 0);
            }
        }
        if (p + 1 < NSTG) __syncthreads();   // phase buffer reuse
    }

    if constexpr (!ISMIX) {
        // conv epilogue: bias, store yc, per-tree stats partials
        float p1 = 0.f, p2 = 0.f;
        #pragma unroll
        for (int rt = 0; rt < 2; ++rt) {
            #pragma unroll
            for (int uu = 0; uu < 4; ++uu) {
                int o = (u0 + uu) * 16 + (l & 15);
                float bcv = bias[o];
                size_t rb = ((size_t)b * N + (n0 + 32 * w + 16 * rt + 4 * (l >> 4))) * CO + o;
                #pragma unroll
                for (int j = 0; j < 4; ++j) {
                    float v = acc[rt][uu][j] + bcv;
                    Y[rb + (size_t)j * CO] = (f16)v;
                    p1 += v; p2 += v * v;
                }
            }
        }
        #pragma unroll
        for (int m = 32; m; m >>= 1) { p1 += __shfl_xor(p1, m); p2 += __shfl_xor(p2, m); }
        if (l == 0) { redu[w * 2] = p1; redu[w * 2 + 1] = p2; }
        __syncthreads();
        if (tid == 0) {
            float t1 = 0.f, t2 = 0.f;
            #pragma unroll
            for (int k = 0; k < 8; ++k) { t1 += redu[2 * k]; t2 += redu[2 * k + 1]; }
            part[(size_t)b * 16 + blockIdx.x * (CO / 64) + blockIdx.y] = make_float2(t1, t2);
        }
    } else {
        // mix epilogue: x = leaky(ym + (yc - mu) * inv), in place over yc
        const float2 st = stats[b];
        #pragma unroll
        for (int rt = 0; rt < 2; ++rt) {
            #pragma unroll
            for (int uu = 0; uu < 4; ++uu) {
                int o = (u0 + uu) * 16 + (l & 15);
                float bmv = bias[o];
                size_t rb = ((size_t)b * N + (n0 + 32 * w + 16 * rt + 4 * (l >> 4))) * CO + o;
                #pragma unroll
                for (int j = 0; j < 4; ++j) {
                    size_t off = rb + (size_t)j * CO;
                    float ycv = (float)Y[off];
                    float v = acc[rt][uu][j] + bmv + (ycv - st.x) * st.y;
                    Y[off] = (f16)leaky(v);
                }
            }
        }
    }
}

__global__ __launch_bounds__(64) void reduce_stats_kernel(
    const float2* __restrict__ part, float2* __restrict__ stats, int nparts, float Mf)
{
    int b = blockIdx.x;
    float s1 = 0.f, s2 = 0.f;
    for (int i = threadIdx.x; i < nparts; i += 64) {
        float2 p = part[(size_t)b * 16 + i];
        s1 += p.x; s2 += p.y;
    }
    #pragma unroll
    for (int m = 32; m; m >>= 1) { s1 += __shfl_xor(s1, m); s2 += __shfl_xor(s2, m); }
    if (threadIdx.x == 0) {
        float mu = s1 / Mf;
        float var = (s2 - s1 * s1 / Mf) / (Mf - 1.f);   // ddof = 1
        var = fmaxf(var, 0.f);
        stats[b] = make_float2(mu, 1.f / (sqrtf(var) + 1e-5f));
    }
}

// fp32 [B][160][N] -> f16 [B][N][160]
__global__ __launch_bounds__(256) void transpose_kernel(
    const float* __restrict__ trees, f16* __restrict__ X0)
{
    __shared__ f16 tile[32][66];
    int b = blockIdx.z, c0 = blockIdx.y * 32, n0 = blockIdx.x * 64;
    int tid = threadIdx.x;
    int nl = tid & 63, c4 = tid >> 6;
    #pragma unroll
    for (int cc = 0; cc < 8; ++cc) {
        int c = c4 * 8 + cc;
        tile[c][nl] = (f16)trees[((size_t)b * 160 + c0 + c) * N + n0 + nl];
    }
    __syncthreads();
    int nn = tid >> 2, gc = tid & 3;
    f16x8 pack;
    #pragma unroll
    for (int e = 0; e < 8; ++e) pack[e] = tile[gc * 8 + e][nn];
    *(f16x8*)(X0 + ((size_t)b * N + n0 + nn) * 160 + c0 + gc * 8) = pack;
}

// weights -> fragment-ready f16 layout: elem ((skk*U+u)*64+l)*8+j  holds
// W[kap = 32*skk+8*(l>>4)+j][o = 16u+(l&15)], kappa-order kap = k*CI + c.
__global__ __launch_bounds__(256) void prepW_kernel(
    const float* __restrict__ Wsrc, f16* __restrict__ out,
    int K, int CO, int CI, int isconv)
{
    int e = blockIdx.x * 256 + threadIdx.x;
    if (e >= K * CO) return;
    int j = e & 7, l = (e >> 3) & 63, r = e >> 9;
    int U = CO / 16;
    int u = r % U, t = r / U;
    int kap = 32 * t + 8 * (l >> 4) + j;
    int o = 16 * u + (l & 15);
    float v = isconv ? Wsrc[((size_t)o * CI + (kap % CI)) * 3 + kap / CI]
                     : Wsrc[(size_t)o * CI + kap];
    out[e] = (f16)v;
}

// masked max-pool over valid nodes + 64->32->1 MLP; x3 is [b][n][64] f16.
__global__ __launch_bounds__(256) void final_kernel(
    const f16* __restrict__ x3, const int* __restrict__ nodes,
    const float* __restrict__ W1, const float* __restrict__ b1,
    const float* __restrict__ W2, const float* __restrict__ b2,
    float* __restrict__ out)
{
    int b = blockIdx.x, tid = threadIdx.x;
    int o = tid & 63, r = tid >> 6;
    int nv = nodes[b];
    const f16* p = x3 + (size_t)b * N * 64 + o;
    float mx = -3.4e38f;
    for (int n = r; n < nv; n += 4) mx = fmaxf(mx, (float)p[(size_t)n * 64]);
    __shared__ float pool[4][64];
    __shared__ float pooled[64], hbuf[32];
    pool[r][o] = mx;
    __syncthreads();
    if (tid < 64) pooled[tid] = fmaxf(fmaxf(pool[0][tid], pool[1][tid]),
                                      fmaxf(pool[2][tid], pool[3][tid]));
    __syncthreads();
    if (tid < 32) {
        float h = b1[tid];
        #pragma unroll 8
        for (int oo = 0; oo < 64; ++oo) h += pooled[oo] * W1[oo * 32 + tid];
        hbuf[tid] = leaky(h);
    }
    __syncthreads();
    if (tid == 0) {
        float rr = b2[0];
        for (int jj = 0; jj < 32; ++jj) rr += hbuf[jj] * W2[jj];
        out[b] = rr;
    }
}

extern "C" void kernel_launch(void* const* d_in, const int* in_sizes, int n_in,
                              void* d_out, int out_size, void* d_ws, size_t ws_size,
                              hipStream_t stream)
{
    (void)in_sizes; (void)n_in; (void)out_size; (void)ws_size;
    const float* trees = (const float*)d_in[0];
    const int* indexes = (const int*)d_in[1];
    const int* nodes   = (const int*)d_in[2];
    const float* Wc1 = (const float*)d_in[3];
    const float* bc1 = (const float*)d_in[4];
    const float* Wm1 = (const float*)d_in[5];
    const float* bm1 = (const float*)d_in[6];
    const float* Wc2 = (const float*)d_in[7];
    const float* bc2 = (const float*)d_in[8];
    const float* Wm2 = (const float*)d_in[9];
    const float* bm2 = (const float*)d_in[10];
    const float* Wc3 = (const float*)d_in[11];
    const float* bc3 = (const float*)d_in[12];
    const float* Wm3 = (const float*)d_in[13];
    const float* bm3 = (const float*)d_in[14];
    const float* W1 = (const float*)d_in[15];
    const float* b1 = (const float*)d_in[16];
    const float* W2 = (const float*)d_in[17];
    const float* b2 = (const float*)d_in[18];
    float* out = (float*)d_out;

    // ws layout:
    //   [0, 83886080)            X0 [B][N][160] f16      -> later yc2/x2 (67MB)
    //   [83886080, 218103808)    yc1/x1 [B][N][256] f16  -> later yc3/x3 (33.5MB)
    //   [218103808, ...)         Wfrags, parts, stats
    char* ws = (char*)d_ws;
    f16* X0 = (f16*)ws;
    f16* A1 = (f16*)(ws + 83886080);
    f16* A2 = (f16*)ws;
    f16* A3 = A1;
    size_t toff = 218103808;
    f16* Wfc1 = (f16*)(ws + toff); toff += (size_t)480 * 256 * 2;
    f16* Wfm1 = (f16*)(ws + toff); toff += (size_t)160 * 256 * 2;
    f16* Wfc2 = (f16*)(ws + toff); toff += (size_t)768 * 128 * 2;
    f16* Wfm2 = (f16*)(ws + toff); toff += (size_t)256 * 128 * 2;
    f16* Wfc3 = (f16*)(ws + toff); toff += (size_t)384 * 64 * 2;
    f16* Wfm3 = (f16*)(ws + toff); toff += (size_t)128 * 64 * 2;
    float2* part  = (float2*)(ws + toff); toff += (size_t)256 * 16 * 8;
    float2* stats = (float2*)(ws + toff);

    transpose_kernel<<<dim3(16, 5, 256), 256, 0, stream>>>(trees, X0);
    prepW_kernel<<<480 * 256 / 256, 256, 0, stream>>>(Wc1, Wfc1, 480, 256, 160, 1);
    prepW_kernel<<<160 * 256 / 256, 256, 0, stream>>>(Wm1, Wfm1, 160, 256, 160, 0);
    prepW_kernel<<<768 * 128 / 256, 256, 0, stream>>>(Wc2, Wfc2, 768, 128, 256, 1);
    prepW_kernel<<<256 * 128 / 256, 256, 0, stream>>>(Wm2, Wfm2, 256, 128, 256, 0);
    prepW_kernel<<<384 * 64 / 256, 256, 0, stream>>>(Wc3, Wfc3, 384, 64, 128, 1);
    prepW_kernel<<<128 * 64 / 256, 256, 0, stream>>>(Wm3, Wfm3, 128, 64, 128, 0);

    // layer 1: CI=160, CO=256
    gemm_kernel<160, 256, 3, 1, false><<<dim3(4, 4, 256), 512, 0, stream>>>(
        X0, indexes, Wfc1, bc1, A1, part, nullptr);
    reduce_stats_kernel<<<256, 64, 0, stream>>>(part, stats, 16, 262144.f);
    gemm_kernel<160, 256, 1, 1, true><<<dim3(4, 4, 256), 512, 0, stream>>>(
        X0, nullptr, Wfm1, bm1, A1, nullptr, stats);

    // layer 2: CI=256, CO=128  (W = 96KB -> 2 staging phases of 48KB)
    gemm_kernel<256, 128, 3, 2, false><<<dim3(4, 2, 256), 512, 0, stream>>>(
        A1, indexes, Wfc2, bc2, A2, part, nullptr);
    reduce_stats_kernel<<<256, 64, 0, stream>>>(part, stats, 8, 131072.f);
    gemm_kernel<256, 128, 1, 1, true><<<dim3(4, 2, 256), 512, 0, stream>>>(
        A1, nullptr, Wfm2, bm2, A2, nullptr, stats);

    // layer 3: CI=128, CO=64
    gemm_kernel<128, 64, 3, 1, false><<<dim3(4, 1, 256), 512, 0, stream>>>(
        A2, indexes, Wfc3, bc3, A3, part, nullptr);
    reduce_stats_kernel<<<256, 64, 0, stream>>>(part, stats, 4, 65536.f);
    gemm_kernel<128, 64, 1, 1, true><<<dim3(4, 1, 256), 512, 0, stream>>>(
        A2, nullptr, Wfm3, bm3, A3, nullptr, stats);

    final_kernel<<<256, 256, 0, stream>>>(A3, nodes, W1, b1, W2, b2, out);
}